// Round 8
// baseline (167.987 us; speedup 1.0000x reference)
//
#include <hip/hip_runtime.h>

// DMV inside (log2-space), one block per batch item, 512 threads = 64 groups of 8.
//  - IR/IL share triangle array sI; FR/FL share sF; diagonal (width-0) = stNC
//    param, selected in-register at the k==w-1 endpoint. CR/CL folded via ghm.
//  - Fused A+B phases: one barrier per width (63 total).
//  - template<NJ> (NJ=ceil(w/8)) block-uniform dispatch: compile-time loop
//    bounds -> straight-line batchable ds_reads.
//  - NEW: template<NJ, ISR> direction specialization. dir/sd are constexpr, so
//    per-j LDS offsets are compile-time immediates (rebased >=0 for dir=-1):
//    kills ~4*NJ per-cell address v_adds and lets the compiler merge
//    contiguous-stream reads into ds_read2_b32. Identical arithmetic.
//  - Group LSE reduce via DPP (quad_perm xor1/xor2 + row_half_mirror).
//  - 4 blocks/CU (LDS 4x37.9K <= 160K), 32 waves/CU, all 1024 blocks resident.
//  - Load balance: pre-kernel counting-sorts items by length; block j takes
//    sorted rank snake(j) (quartile snake) so co-resident blocks
//    {j, j+256, j+512, j+768} span the work quartiles (R7: 127->83.6 us).

#define NEGV   -1000000000.0f
#define NMAX   64
#define LDS_S  69
#define BLOCK  512
#define NGROUPS (BLOCK / 8)   // 64

#if __has_builtin(__builtin_amdgcn_exp2f)
#define EXP2F(x) __builtin_amdgcn_exp2f(x)
#else
#define EXP2F(x) __expf((x) * 0.6931471805599453f)
#endif
#if __has_builtin(__builtin_amdgcn_logf)
#define LOG2F(x) __builtin_amdgcn_logf(x)
#else
#define LOG2F(x) (__logf(x) * 1.4426950408889634f)
#endif
#define LOG2E 1.4426950408889634f
#define LN2   0.6931471805599453f

template<int CTRL>
__device__ __forceinline__ float dppf(float v) {
    return __int_as_float(__builtin_amdgcn_update_dpp(
        0, __float_as_int(v), CTRL, 0xF, 0xF, true));
}
__device__ __forceinline__ float grp8_max(float m) {
    m = fmaxf(m, dppf<0xB1>(m));    // quad_perm xor 1
    m = fmaxf(m, dppf<0x4E>(m));    // quad_perm xor 2
    m = fmaxf(m, dppf<0x141>(m));   // row_half_mirror (joins quads in 8-lane group)
    return m;
}
__device__ __forceinline__ float grp8_sum(float s) {
    s += dppf<0xB1>(s);
    s += dppf<0x4E>(s);
    s += dppf<0x141>(s);
    return s;
}

__device__ __forceinline__ void lse_merge(float& m, float& s, float mo, float so) {
    float mn = fmaxf(m, mo);
    s = s * EXP2F(m - mn) + so * EXP2F(mo - mn);
    m = mn;
}

// ---- pre-kernel: counting sort by length (descending) + quartile-snake map ----
__global__ void order_kernel(const int* __restrict__ len_arr,
                             int* __restrict__ blk2item, int B)
{
    __shared__ int hist[33];
    __shared__ int base[33];
    const int tid = threadIdx.x;
    if (tid < 33) hist[tid] = 0;
    __syncthreads();
    int bin = 0;
    if (tid < B) {
        bin = 64 - len_arr[tid];          // 0 = longest
        atomicAdd(&hist[bin], 1);
    }
    __syncthreads();
    if (tid == 0) {
        int acc = 0;
        for (int i = 0; i < 33; ++i) { base[i] = acc; acc += hist[i]; }
    }
    __syncthreads();
    if (tid < B) {
        int rank = atomicAdd(&base[bin], 1);   // sorted-descending rank
        int j;
        if ((B & 255) == 0) {                   // snake across quartile stripes
            int q = rank >> 8, pos = rank & 255;
            j = (q & 1) ? ((q << 8) + 255 - pos) : ((q << 8) + pos);
        } else {
            j = rank;
        }
        blk2item[j] = tid;
    }
}

// One fused A+B cell. NJ = ceil(w/8) and direction are compile-time.
template<int NJ, bool ISR>
__device__ __forceinline__ void dmv_cell(
    const int w, const int h, const int e, const int lg,
    float* __restrict__ sI, float* __restrict__ sF,
    const float* __restrict__ goNC, const float* __restrict__ goHM,
    const float* __restrict__ stHC, const float* __restrict__ stNC,
    const int* __restrict__ th_s, const float* __restrict__ trans_param)
{
    constexpr int SD  = ISR ? 1 : 0;
    constexpr int DIR = ISR ? 1 : -1;
    constexpr int RB  = 8 * (NJ - 1);      // rebase so all imm offsets >= 0

    // ---- phase A: I[h][e] = tr + lse_k( C[h][h+DIR*k]+go + F_other ) ----
    const float tr  = trans_param[(th_s[h] * NMAX + th_s[e]) * 2 + SD] * LOG2E;
    const float gnc = goNC[SD * NMAX + h];
    const float ghm = goHM[SD * NMAX + h];
    const float dcO = stNC[(SD ^ 1) * NMAX + e];

    // lane-resolved stream bases; per-j offsets are compile-time constants
    const float* A1 = sF + h * LDS_S + h + DIR * lg + (ISR ? 0 : -RB);       // own F row
    const float* A2 = sF + e * LDS_S + h + DIR + DIR * lg + (ISR ? 0 : -RB); // other F row
    float x[NJ];
    #pragma unroll
    for (int j = 0; j < NJ; ++j) {
        const int k = lg + 8 * j;
        if (j == NJ - 1) {                    // endpoint handling (runtime addr ok)
            const int kc = (k < w - 1) ? k : (w - 1);
            float vF = sF[h * LDS_S + h + DIR * kc];
            float vC = (k == w - 1) ? dcO : sF[e * LDS_S + h + DIR + DIR * kc];
            float base = (k == 0) ? gnc : (vF + ghm);
            float v = base + vC;
            x[j] = (k < w) ? v : NEGV;
        } else {
            constexpr int OFF = ISR ? 8 * 0 : RB;   // placeholder; real below
            (void)OFF;
            const int o = ISR ? 8 * j : (RB - 8 * j);   // compile-time per unrolled j
            float vF = A1[o];
            float vC = A2[o];
            float base = (j == 0 && k == 0) ? gnc : (vF + ghm);
            x[j] = base + vC;
        }
    }
    float mA = x[0];
    #pragma unroll
    for (int j = 1; j < NJ; ++j) mA = fmaxf(mA, x[j]);
    mA = grp8_max(mA);
    float sA = 0.f;
    #pragma unroll
    for (int j = 0; j < NJ; ++j) sA += EXP2F(x[j] - mA);
    sA = grp8_sum(sA);
    const float ir = mA + LOG2F(sA) + tr;
    if (lg == 0) sI[h * LDS_S + e] = ir;

    // ---- phase B (fused): F[h][e] = lse_k( I[h][h+DIR*(k+1)] + F[h+DIR*(k+1)][e] ) + st_hc ----
    const float dcN = stNC[SD * NMAX + e];
    const float sth = stHC[SD * NMAX + h];
    const float* B1 = sI + h * LDS_S + h + DIR + DIR * lg + (ISR ? 0 : -RB);
    const float* B2 = sF + (h + DIR) * LDS_S + e + DIR * lg * LDS_S
                         + (ISR ? 0 : -RB * LDS_S);
    float y[NJ];
    #pragma unroll
    for (int j = 0; j < NJ; ++j) {
        const int k = lg + 8 * j;
        if (j == NJ - 1) {
            const int kc = (k < w - 1) ? k : (w - 1);
            float v1 = (k == w - 1) ? ir  : sI[h * LDS_S + h + DIR + DIR * kc];
            float v2 = (k == w - 1) ? dcN : sF[(h + DIR) * LDS_S + e + DIR * kc * LDS_S];
            float v  = v1 + v2;
            y[j] = (k < w) ? v : NEGV;
        } else {
            const int o  = ISR ? 8 * j : (RB - 8 * j);          // contiguous stream
            const int os = (ISR ? 8 * j : (RB - 8 * j)) * LDS_S; // strided stream
            y[j] = B1[o] + B2[os];
        }
    }
    float mB = y[0];
    #pragma unroll
    for (int j = 1; j < NJ; ++j) mB = fmaxf(mB, y[j]);
    mB = grp8_max(mB);
    float sB = 0.f;
    #pragma unroll
    for (int j = 0; j < NJ; ++j) sB += EXP2F(y[j] - mB);
    sB = grp8_sum(sB);
    if (lg == 0) sF[h * LDS_S + e] = mB + LOG2F(sB) + sth;
}

template<int NJ>
__device__ __forceinline__ void dmv_step(
    const int w, const int cd, const int gid, const int lg,
    float* __restrict__ sI, float* __restrict__ sF,
    const float* __restrict__ goNC, const float* __restrict__ goHM,
    const float* __restrict__ stHC, const float* __restrict__ stNC,
    const int* __restrict__ th_s, const float* __restrict__ trans_param)
{
    const int cells = 2 * cd;
    for (int ci = gid; ci < cells; ci += NGROUPS) {
        if (ci < cd) {                    // right-direction cell
            dmv_cell<NJ, true>(w, ci, ci + w, lg, sI, sF,
                               goNC, goHM, stHC, stNC, th_s, trans_param);
        } else {                          // left-direction cell
            const int h = w + ci - cd;
            dmv_cell<NJ, false>(w, h, h - w, lg, sI, sF,
                                goNC, goHM, stHC, stNC, th_s, trans_param);
        }
    }
}

__global__ __launch_bounds__(BLOCK, 8)
void dmv_inside_kernel(const int* __restrict__ tag,
                       const int* __restrict__ len_arr,
                       const float* __restrict__ root_param,
                       const float* __restrict__ trans_param,
                       const float* __restrict__ dec_param,
                       const int* __restrict__ blk2item,
                       float* __restrict__ out)
{
    __shared__ float sI[NMAX * LDS_S];     // IR upper / IL lower triangle
    __shared__ float sF[NMAX * LDS_S];     // FR upper / FL lower triangle
    __shared__ float goNC[2 * NMAX];       // [0]=L, [1]=R (log2-scaled)
    __shared__ float goHM[2 * NMAX];       // go_hc - st_hc
    __shared__ float stHC[2 * NMAX];
    __shared__ float stNC[2 * NMAX];       // the "diagonal" of F
    __shared__ float root_s[NMAX];
    __shared__ int   th_s[NMAX];

    const int b   = blk2item[blockIdx.x];  // balanced assignment
    const int tid = threadIdx.x;
    const int nl  = len_arr[b];            // 32..64; output depends only on [0,nl)

    if (tid < NMAX) {
        int t = tag[b * NMAX + tid];
        th_s[tid] = t;
        const float* d = dec_param + t * 8;   // [dir][val][dec], L=0 R=1
        goNC[0 * NMAX + tid] = d[0] * LOG2E;
        stNC[0 * NMAX + tid] = d[1] * LOG2E;
        goHM[0 * NMAX + tid] = (d[2] - d[3]) * LOG2E;
        stHC[0 * NMAX + tid] = d[3] * LOG2E;
        goNC[1 * NMAX + tid] = d[4] * LOG2E;
        stNC[1 * NMAX + tid] = d[5] * LOG2E;
        goHM[1 * NMAX + tid] = (d[6] - d[7]) * LOG2E;
        stHC[1 * NMAX + tid] = d[7] * LOG2E;
        root_s[tid]          = root_param[t] * LOG2E;
    }
    __syncthreads();

    const int gid = tid >> 3;      // 0..63 — one DP cell per group per trip
    const int lg  = tid & 7;

    for (int w = 1; w < nl; ++w) {
        const int cd = nl - w;
        switch ((w - 1) >> 3) {    // block-uniform scalar dispatch
        case 0: dmv_step<1>(w, cd, gid, lg, sI, sF, goNC, goHM, stHC, stNC, th_s, trans_param); break;
        case 1: dmv_step<2>(w, cd, gid, lg, sI, sF, goNC, goHM, stHC, stNC, th_s, trans_param); break;
        case 2: dmv_step<3>(w, cd, gid, lg, sI, sF, goNC, goHM, stHC, stNC, th_s, trans_param); break;
        case 3: dmv_step<4>(w, cd, gid, lg, sI, sF, goNC, goHM, stHC, stNC, th_s, trans_param); break;
        case 4: dmv_step<5>(w, cd, gid, lg, sI, sF, goNC, goHM, stHC, stNC, th_s, trans_param); break;
        case 5: dmv_step<6>(w, cd, gid, lg, sI, sF, goNC, goHM, stHC, stNC, th_s, trans_param); break;
        case 6: dmv_step<7>(w, cd, gid, lg, sI, sF, goNC, goHM, stHC, stNC, th_s, trans_param); break;
        default: dmv_step<8>(w, cd, gid, lg, sI, sF, goNC, goHM, stHC, stNC, th_s, trans_param); break;
        }
        __syncthreads();
    }

    // ---- final: out[b] = ln2 * lse_i( root[i] + FL[i][0] + FR[i][last] ), i<nl ----
    if (tid < 64) {
        const int last = nl - 1;
        float fl0 = (tid == 0)    ? stNC[0 * NMAX + 0]    : sF[tid * LDS_S + 0];
        float fre = (tid == last) ? stNC[1 * NMAX + last] : sF[tid * LDS_S + last];
        float xx  = (tid < nl) ? (root_s[tid] + fl0 + fre) : NEGV;
        float m = xx, s = 1.0f;
        #pragma unroll
        for (int off = 1; off < 64; off <<= 1)
            lse_merge(m, s, __shfl_xor(m, off, 64), __shfl_xor(s, off, 64));
        if (tid == 0) out[b] = (m + LOG2F(s)) * LN2;
    }
}

extern "C" void kernel_launch(void* const* d_in, const int* in_sizes, int n_in,
                              void* d_out, int out_size, void* d_ws, size_t ws_size,
                              hipStream_t stream) {
    // setup_inputs order: id_array, tag_array, len_array, root_param, trans_param, dec_param
    const int*   tag   = (const int*)d_in[1];
    const int*   len_a = (const int*)d_in[2];
    const float* root  = (const float*)d_in[3];
    const float* trans = (const float*)d_in[4];
    const float* dec   = (const float*)d_in[5];
    float* outp = (float*)d_out;
    const int B = in_sizes[2];   // 1024

    int* blk2item = (int*)d_ws;  // B ints

    int sortThreads = (B < 1024) ? ((B + 63) & ~63) : 1024;
    if (sortThreads < 64) sortThreads = 64;
    order_kernel<<<1, sortThreads, 0, stream>>>(len_a, blk2item, B);
    dmv_inside_kernel<<<B, BLOCK, 0, stream>>>(tag, len_a, root, trans, dec,
                                               blk2item, outp);
}

// Round 9
// 72.317 us; speedup vs baseline: 2.3229x; 2.3229x over previous
//
#include <hip/hip_runtime.h>

// DMV inside (log2-space), one block per batch item, 512 threads = 128 groups of 4.
//  - IR/IL share triangle array sI; FR/FL share sF; diagonal (width-0) = stNC
//    param, selected in-register at the k==w-1 endpoint. CR/CL folded via ghm.
//  - Fused A+B phases: one barrier per width (63 total).
//  - template<NJ> (NJ=ceil(w/4), 16 cases) block-uniform dispatch: compile-time
//    loop bounds -> straight-line batchable ds_reads. Runtime dir (single cell
//    body): the R8 ISR-split + rebased pointers caused SROA failure -> 440 MB
//    scratch spill -> 2x regression. Do not re-introduce.
//  - 4-LANE groups: 16 cells/wave (2x fixed-cost amortization: 2-op DPP
//    reduce via quad_perm xor1/xor2), 128 groups >= 126 cells -> single trip
//    for every width (no second serial cell-chain on small-w steps).
//  - 4 blocks/CU (LDS 4x37.9K <= 160K), 32 waves/CU, all 1024 blocks resident.
//  - Load balance: pre-kernel counting-sorts items by length; block j takes
//    sorted rank snake(j) (quartile snake) so co-resident blocks
//    {j, j+256, j+512, j+768} span the work quartiles (R7: 127->83.6 us).

#define NEGV   -1000000000.0f
#define NMAX   64
#define LDS_S  69
#define BLOCK  512
#define NGROUPS (BLOCK / 4)   // 128

#if __has_builtin(__builtin_amdgcn_exp2f)
#define EXP2F(x) __builtin_amdgcn_exp2f(x)
#else
#define EXP2F(x) __expf((x) * 0.6931471805599453f)
#endif
#if __has_builtin(__builtin_amdgcn_logf)
#define LOG2F(x) __builtin_amdgcn_logf(x)
#else
#define LOG2F(x) (__logf(x) * 1.4426950408889634f)
#endif
#define LOG2E 1.4426950408889634f
#define LN2   0.6931471805599453f

template<int CTRL>
__device__ __forceinline__ float dppf(float v) {
    return __int_as_float(__builtin_amdgcn_update_dpp(
        0, __float_as_int(v), CTRL, 0xF, 0xF, true));
}
// 4-lane (quad) reductions — groups are lanes [4g..4g+3]:
__device__ __forceinline__ float grp4_max(float m) {
    m = fmaxf(m, dppf<0xB1>(m));    // quad_perm xor 1
    m = fmaxf(m, dppf<0x4E>(m));    // quad_perm xor 2
    return m;
}
__device__ __forceinline__ float grp4_sum(float s) {
    s += dppf<0xB1>(s);
    s += dppf<0x4E>(s);
    return s;
}

__device__ __forceinline__ void lse_merge(float& m, float& s, float mo, float so) {
    float mn = fmaxf(m, mo);
    s = s * EXP2F(m - mn) + so * EXP2F(mo - mn);
    m = mn;
}

// ---- pre-kernel: counting sort by length (descending) + quartile-snake map ----
__global__ void order_kernel(const int* __restrict__ len_arr,
                             int* __restrict__ blk2item, int B)
{
    __shared__ int hist[33];
    __shared__ int base[33];
    const int tid = threadIdx.x;
    if (tid < 33) hist[tid] = 0;
    __syncthreads();
    int bin = 0;
    if (tid < B) {
        bin = 64 - len_arr[tid];          // 0 = longest
        atomicAdd(&hist[bin], 1);
    }
    __syncthreads();
    if (tid == 0) {
        int acc = 0;
        for (int i = 0; i < 33; ++i) { base[i] = acc; acc += hist[i]; }
    }
    __syncthreads();
    if (tid < B) {
        int rank = atomicAdd(&base[bin], 1);   // sorted-descending rank
        int j;
        if ((B & 255) == 0) {                   // snake across quartile stripes
            int q = rank >> 8, pos = rank & 255;
            j = (q & 1) ? ((q << 8) + 255 - pos) : ((q << 8) + pos);
        } else {
            j = rank;
        }
        blk2item[j] = tid;
    }
}

// Fused A+B step for this group's cell. NJ = ceil(w/4) known at compile time.
template<int NJ>
__device__ __forceinline__ void dmv_step(
    const int w, const int cd, const int gid, const int lg,
    float* __restrict__ sI, float* __restrict__ sF,
    const float* __restrict__ goNC, const float* __restrict__ goHM,
    const float* __restrict__ stHC, const float* __restrict__ stNC,
    const int* __restrict__ th_s, const float* __restrict__ trans_param)
{
    const int cells = 2 * cd;
    if (gid >= cells) return;             // 128 groups >= 126 cells: single trip
    const bool isR = gid < cd;
    const int  sd  = isR ? 1 : 0;
    const int  dir = isR ? 1 : -1;
    const int  h   = isR ? gid : (w + gid - cd);
    const int  e   = h + dir * w;

    // ---- phase A: I[h][e] = tr + lse_k( C[h][h+dir*k]+go + F_other ) ----
    const float tr  = trans_param[(th_s[h] * NMAX + th_s[e]) * 2 + sd] * LOG2E;
    const float gnc = goNC[sd * NMAX + h];
    const float ghm = goHM[sd * NMAX + h];
    const float dcO = stNC[(sd ^ 1) * NMAX + e];
    const int   oF  = h * LDS_S + h;        // own F row,   elem [dir*k]
    const int   oC  = e * LDS_S + h + dir;  // other F row, elem [dir*k]
    float x[NJ];
    #pragma unroll
    for (int j = 0; j < NJ; ++j) {
        const int k = lg + 4 * j;
        if (j == NJ - 1) {                   // static: endpoint handling here only
            const int  kc = (k < w - 1) ? k : (w - 1);
            float vF = sF[oF + dir * kc];
            float vC = (k == w - 1) ? dcO : sF[oC + dir * kc];
            float base = (k == 0) ? gnc : (vF + ghm);
            float v = base + vC;
            x[j] = (k < w) ? v : NEGV;
        } else {
            float vF = sF[oF + dir * k];
            float vC = sF[oC + dir * k];
            float base = (j == 0 && k == 0) ? gnc : (vF + ghm);
            x[j] = base + vC;
        }
    }
    float mA = x[0];
    #pragma unroll
    for (int j = 1; j < NJ; ++j) mA = fmaxf(mA, x[j]);
    mA = grp4_max(mA);
    float sA = 0.f;
    #pragma unroll
    for (int j = 0; j < NJ; ++j) sA += EXP2F(x[j] - mA);
    sA = grp4_sum(sA);
    const float ir = mA + LOG2F(sA) + tr;
    if (lg == 0) sI[h * LDS_S + e] = ir;

    // ---- phase B (fused): F[h][e] = lse_k( I[h][h+dir*(k+1)] + F[h+dir*(k+1)][e] ) + st_hc ----
    const float dcN = stNC[sd * NMAX + e];
    const float sth = stHC[sd * NMAX + h];
    const int   oI  = h * LDS_S + h + dir;    // elem [dir*k]
    const int   oF2 = (h + dir) * LDS_S + e;  // elem [dir*k*LDS_S]
    float y[NJ];
    #pragma unroll
    for (int j = 0; j < NJ; ++j) {
        const int k = lg + 4 * j;
        if (j == NJ - 1) {
            const int  kc = (k < w - 1) ? k : (w - 1);
            float v1 = (k == w - 1) ? ir  : sI[oI + dir * kc];
            float v2 = (k == w - 1) ? dcN : sF[oF2 + dir * kc * LDS_S];
            float v  = v1 + v2;
            y[j] = (k < w) ? v : NEGV;
        } else {
            y[j] = sI[oI + dir * k] + sF[oF2 + dir * k * LDS_S];
        }
    }
    float mB = y[0];
    #pragma unroll
    for (int j = 1; j < NJ; ++j) mB = fmaxf(mB, y[j]);
    mB = grp4_max(mB);
    float sB = 0.f;
    #pragma unroll
    for (int j = 0; j < NJ; ++j) sB += EXP2F(y[j] - mB);
    sB = grp4_sum(sB);
    if (lg == 0) sF[h * LDS_S + e] = mB + LOG2F(sB) + sth;
}

__global__ __launch_bounds__(BLOCK, 8)
void dmv_inside_kernel(const int* __restrict__ tag,
                       const int* __restrict__ len_arr,
                       const float* __restrict__ root_param,
                       const float* __restrict__ trans_param,
                       const float* __restrict__ dec_param,
                       const int* __restrict__ blk2item,
                       float* __restrict__ out)
{
    __shared__ float sI[NMAX * LDS_S];     // IR upper / IL lower triangle
    __shared__ float sF[NMAX * LDS_S];     // FR upper / FL lower triangle
    __shared__ float goNC[2 * NMAX];       // [0]=L, [1]=R (log2-scaled)
    __shared__ float goHM[2 * NMAX];       // go_hc - st_hc
    __shared__ float stHC[2 * NMAX];
    __shared__ float stNC[2 * NMAX];       // the "diagonal" of F
    __shared__ float root_s[NMAX];
    __shared__ int   th_s[NMAX];

    const int b   = blk2item[blockIdx.x];  // balanced assignment
    const int tid = threadIdx.x;
    const int nl  = len_arr[b];            // 32..64; output depends only on [0,nl)

    if (tid < NMAX) {
        int t = tag[b * NMAX + tid];
        th_s[tid] = t;
        const float* d = dec_param + t * 8;   // [dir][val][dec], L=0 R=1
        goNC[0 * NMAX + tid] = d[0] * LOG2E;
        stNC[0 * NMAX + tid] = d[1] * LOG2E;
        goHM[0 * NMAX + tid] = (d[2] - d[3]) * LOG2E;
        stHC[0 * NMAX + tid] = d[3] * LOG2E;
        goNC[1 * NMAX + tid] = d[4] * LOG2E;
        stNC[1 * NMAX + tid] = d[5] * LOG2E;
        goHM[1 * NMAX + tid] = (d[6] - d[7]) * LOG2E;
        stHC[1 * NMAX + tid] = d[7] * LOG2E;
        root_s[tid]          = root_param[t] * LOG2E;
    }
    __syncthreads();

    const int gid = tid >> 2;      // 0..127 — one DP cell per 4-lane group
    const int lg  = tid & 3;

    for (int w = 1; w < nl; ++w) {
        const int cd = nl - w;
        switch ((w - 1) >> 2) {    // block-uniform scalar dispatch, NJ=ceil(w/4)
        case  0: dmv_step< 1>(w, cd, gid, lg, sI, sF, goNC, goHM, stHC, stNC, th_s, trans_param); break;
        case  1: dmv_step< 2>(w, cd, gid, lg, sI, sF, goNC, goHM, stHC, stNC, th_s, trans_param); break;
        case  2: dmv_step< 3>(w, cd, gid, lg, sI, sF, goNC, goHM, stHC, stNC, th_s, trans_param); break;
        case  3: dmv_step< 4>(w, cd, gid, lg, sI, sF, goNC, goHM, stHC, stNC, th_s, trans_param); break;
        case  4: dmv_step< 5>(w, cd, gid, lg, sI, sF, goNC, goHM, stHC, stNC, th_s, trans_param); break;
        case  5: dmv_step< 6>(w, cd, gid, lg, sI, sF, goNC, goHM, stHC, stNC, th_s, trans_param); break;
        case  6: dmv_step< 7>(w, cd, gid, lg, sI, sF, goNC, goHM, stHC, stNC, th_s, trans_param); break;
        case  7: dmv_step< 8>(w, cd, gid, lg, sI, sF, goNC, goHM, stHC, stNC, th_s, trans_param); break;
        case  8: dmv_step< 9>(w, cd, gid, lg, sI, sF, goNC, goHM, stHC, stNC, th_s, trans_param); break;
        case  9: dmv_step<10>(w, cd, gid, lg, sI, sF, goNC, goHM, stHC, stNC, th_s, trans_param); break;
        case 10: dmv_step<11>(w, cd, gid, lg, sI, sF, goNC, goHM, stHC, stNC, th_s, trans_param); break;
        case 11: dmv_step<12>(w, cd, gid, lg, sI, sF, goNC, goHM, stHC, stNC, th_s, trans_param); break;
        case 12: dmv_step<13>(w, cd, gid, lg, sI, sF, goNC, goHM, stHC, stNC, th_s, trans_param); break;
        case 13: dmv_step<14>(w, cd, gid, lg, sI, sF, goNC, goHM, stHC, stNC, th_s, trans_param); break;
        case 14: dmv_step<15>(w, cd, gid, lg, sI, sF, goNC, goHM, stHC, stNC, th_s, trans_param); break;
        default: dmv_step<16>(w, cd, gid, lg, sI, sF, goNC, goHM, stHC, stNC, th_s, trans_param); break;
        }
        __syncthreads();
    }

    // ---- final: out[b] = ln2 * lse_i( root[i] + FL[i][0] + FR[i][last] ), i<nl ----
    if (tid < 64) {
        const int last = nl - 1;
        float fl0 = (tid == 0)    ? stNC[0 * NMAX + 0]    : sF[tid * LDS_S + 0];
        float fre = (tid == last) ? stNC[1 * NMAX + last] : sF[tid * LDS_S + last];
        float xx  = (tid < nl) ? (root_s[tid] + fl0 + fre) : NEGV;
        float m = xx, s = 1.0f;
        #pragma unroll
        for (int off = 1; off < 64; off <<= 1)
            lse_merge(m, s, __shfl_xor(m, off, 64), __shfl_xor(s, off, 64));
        if (tid == 0) out[b] = (m + LOG2F(s)) * LN2;
    }
}

extern "C" void kernel_launch(void* const* d_in, const int* in_sizes, int n_in,
                              void* d_out, int out_size, void* d_ws, size_t ws_size,
                              hipStream_t stream) {
    // setup_inputs order: id_array, tag_array, len_array, root_param, trans_param, dec_param
    const int*   tag   = (const int*)d_in[1];
    const int*   len_a = (const int*)d_in[2];
    const float* root  = (const float*)d_in[3];
    const float* trans = (const float*)d_in[4];
    const float* dec   = (const float*)d_in[5];
    float* outp = (float*)d_out;
    const int B = in_sizes[2];   // 1024

    int* blk2item = (int*)d_ws;  // B ints

    int sortThreads = (B < 1024) ? ((B + 63) & ~63) : 1024;
    if (sortThreads < 64) sortThreads = 64;
    order_kernel<<<1, sortThreads, 0, stream>>>(len_a, blk2item, B);
    dmv_inside_kernel<<<B, BLOCK, 0, stream>>>(tag, len_a, root, trans, dec,
                                               blk2item, outp);
}